// Round 1
// baseline (13130.711 us; speedup 1.0000x reference)
//
#include <hip/hip_runtime.h>
#include <math.h>

namespace {
constexpr int B_ = 128;
constexpr int T_ = 256;
constexpr int D_ = 512;
constexpr int U_ = 1024;
constexpr int K_TOT = D_ + U_;     // 1536
constexpr int BM = 32;             // batch tile
constexpr int BN = 16;             // u tile (per gate)
constexpr int KC = 128;            // k chunk
}

#define E_CONST 2.71828182845904523536f

// One GRU timestep: h_next[b,u] = z*h_dec + (1-z)*tanh(xh + ibh + r*(rech + rbh))
// grid = (U/BN, B/BM), block = 256 threads.
// Thread (ux = tid&15, ty = tid>>4) computes rows {b0+ty, b0+ty+16}, col u0+ux.
__global__ __launch_bounds__(256) void tgru_step(
    const float* __restrict__ seq,     // [B,T,D]
    const float* __restrict__ dts,     // [B,T]
    const float* __restrict__ Wk,      // [D,3U]
    const float* __restrict__ Wr,      // [U,3U]
    const float* __restrict__ ib,      // [3U]
    const float* __restrict__ rb,      // [3U]
    const float* __restrict__ h_prev,  // [B,U]
    float* __restrict__ h_next,        // [B,U]
    int t)
{
    __shared__ float act[BM][KC + 4];          // [x_t | h*decay] chunk
    __shared__ float wt[3 * BN][KC + 4];       // transposed weights: wt[c][kk]

    const int tid = threadIdx.x;
    const int ux = tid & 15;
    const int ty = tid >> 4;
    const int u0 = blockIdx.x * BN;
    const int b0 = blockIdx.y * BM;

    float accz[2]  = {0.f, 0.f};
    float accr[2]  = {0.f, 0.f};
    float acchx[2] = {0.f, 0.f};   // x-part of h gate (gets ib only)
    float acchr[2] = {0.f, 0.f};   // recurrent part of h gate (gets rb, multiplied by r)

    const int r_stage = tid >> 3;   // 0..31 (row)
    const int c4_stage = tid & 7;   // 0..7  (float4 col base)

#define TGRU_KLOOP(HXACC)                                                         \
    _Pragma("unroll 2")                                                           \
    for (int kk = 0; kk < KC; kk += 4) {                                          \
        const float4 wz  = *reinterpret_cast<const float4*>(&wt[ux][kk]);         \
        const float4 wrr = *reinterpret_cast<const float4*>(&wt[16 + ux][kk]);    \
        const float4 wh  = *reinterpret_cast<const float4*>(&wt[32 + ux][kk]);    \
        _Pragma("unroll")                                                         \
        for (int rr = 0; rr < 2; ++rr) {                                          \
            const float4 a = *reinterpret_cast<const float4*>(&act[ty + 16 * rr][kk]); \
            accz[rr] = fmaf(a.x, wz.x, accz[rr]);                                 \
            accz[rr] = fmaf(a.y, wz.y, accz[rr]);                                 \
            accz[rr] = fmaf(a.z, wz.z, accz[rr]);                                 \
            accz[rr] = fmaf(a.w, wz.w, accz[rr]);                                 \
            accr[rr] = fmaf(a.x, wrr.x, accr[rr]);                                \
            accr[rr] = fmaf(a.y, wrr.y, accr[rr]);                                \
            accr[rr] = fmaf(a.z, wrr.z, accr[rr]);                                \
            accr[rr] = fmaf(a.w, wrr.w, accr[rr]);                                \
            HXACC[rr] = fmaf(a.x, wh.x, HXACC[rr]);                               \
            HXACC[rr] = fmaf(a.y, wh.y, HXACC[rr]);                               \
            HXACC[rr] = fmaf(a.z, wh.z, HXACC[rr]);                               \
            HXACC[rr] = fmaf(a.w, wh.w, HXACC[rr]);                               \
        }                                                                         \
    }

    #pragma unroll 1
    for (int kc = 0; kc < K_TOT; kc += KC) {
        const bool is_x = (kc < D_);

        // ---- stage activation chunk act[32][128] ----
        {
            const int b = b0 + r_stage;
            if (is_x) {
                const float4* src = reinterpret_cast<const float4*>(
                    seq + (size_t)b * (T_ * D_) + (size_t)t * D_ + kc);
                #pragma unroll
                for (int i = 0; i < 4; ++i) {
                    const int c = c4_stage + 8 * i;
                    *reinterpret_cast<float4*>(&act[r_stage][4 * c]) = src[c];
                }
            } else {
                const float dec = 1.0f / logf(E_CONST + dts[b * T_ + t]);
                const float4* src = reinterpret_cast<const float4*>(
                    h_prev + (size_t)b * U_ + (kc - D_));
                #pragma unroll
                for (int i = 0; i < 4; ++i) {
                    const int c = c4_stage + 8 * i;
                    float4 v = src[c];
                    v.x *= dec; v.y *= dec; v.z *= dec; v.w *= dec;
                    *reinterpret_cast<float4*>(&act[r_stage][4 * c]) = v;
                }
            }
        }
        // ---- stage weight chunk wt[48][128] (transposed) ----
        {
            const float* __restrict__ Wsrc = is_x ? Wk : Wr;
            const int krow0 = is_x ? kc : (kc - D_);
            #pragma unroll
            for (int i = 0; i < 24; ++i) {
                const int idx = tid + 256 * i;      // 0..6143
                const int kk = idx / 48;
                const int c = idx - kk * 48;        // 0..47 : gate*16 + ul
                const int g = c >> 4;
                const int ul = c & 15;
                wt[c][kk] = Wsrc[(size_t)(krow0 + kk) * (3 * U_) + g * U_ + u0 + ul];
            }
        }
        __syncthreads();

        if (is_x) { TGRU_KLOOP(acchx) } else { TGRU_KLOOP(acchr) }

        __syncthreads();
    }
#undef TGRU_KLOOP

    // ---- gates + blend ----
    const int u = u0 + ux;
    const float ibz = ib[u], ibr = ib[U_ + u], ibh = ib[2 * U_ + u];
    const float rbz = rb[u], rbr = rb[U_ + u], rbh = rb[2 * U_ + u];

    #pragma unroll
    for (int rr = 0; rr < 2; ++rr) {
        const int b = b0 + ty + 16 * rr;
        const float dec = 1.0f / logf(E_CONST + dts[b * T_ + t]);
        const float hdec_u = h_prev[(size_t)b * U_ + u] * dec;
        const float z = 1.0f / (1.0f + expf(-(accz[rr] + ibz + rbz)));
        const float r = 1.0f / (1.0f + expf(-(accr[rr] + ibr + rbr)));
        const float hh = tanhf(acchx[rr] + ibh + r * (acchr[rr] + rbh));
        h_next[(size_t)b * U_ + u] = z * hdec_u + (1.0f - z) * hh;
    }
}

extern "C" void kernel_launch(void* const* d_in, const int* in_sizes, int n_in,
                              void* d_out, int out_size, void* d_ws, size_t ws_size,
                              hipStream_t stream) {
    const float* seq = (const float*)d_in[0];  // sequences [B,T,D]
    const float* dts = (const float*)d_in[1];  // time_deltas [B,T]
    const float* Wk  = (const float*)d_in[2];  // kernel [D,3U]
    const float* Wr  = (const float*)d_in[3];  // recurrent_kernel [U,3U]
    const float* ib  = (const float*)d_in[4];  // input_bias [3U]
    const float* rb  = (const float*)d_in[5];  // recurrent_bias [3U]

    float* out = (float*)d_out;                // final h [B,U]; also ping buffer
    float* hws = (float*)d_ws;                 // pong buffer [B,U] (512 KB)

    // h0 = 0 in the "out" buffer (read by t=0). Deterministic per launch.
    hipMemsetAsync(out, 0, (size_t)B_ * U_ * sizeof(float), stream);

    dim3 grid(U_ / BN, B_ / BM);
    dim3 block(256);

    // Parity: even t reads out -> writes ws; odd t reads ws -> writes out.
    // t = 255 (odd) writes d_out: final state lands in d_out.
    for (int t = 0; t < T_; ++t) {
        const float* hp = (t & 1) ? hws : out;
        float* hn = (t & 1) ? out : hws;
        tgru_step<<<grid, block, 0, stream>>>(seq, dts, Wk, Wr, ib, rb, hp, hn, t);
    }
}

// Round 2
// 12941.574 us; speedup vs baseline: 1.0146x; 1.0146x over previous
//
#include <hip/hip_runtime.h>
#include <math.h>

namespace {
constexpr int B_ = 128;
constexpr int T_ = 256;
constexpr int D_ = 512;
constexpr int U_ = 1024;
constexpr int N3U = 3 * U_;        // 3072
constexpr int K_TOT = D_ + U_;     // 1536
}

#define E_CONST 2.71828182845904523536f

using bf16x8 = __attribute__((ext_vector_type(8))) short;
using f32x4  = __attribute__((ext_vector_type(4))) float;

__device__ inline unsigned short f2bf(float f) {
    union { float f; unsigned int u; } a; a.f = f;
    unsigned int u = a.u;
    return (unsigned short)((u + 0x7FFFu + ((u >> 16) & 1u)) >> 16);  // RNE
}

__device__ inline bf16x8 ldb16(const unsigned short* p) {
    return *reinterpret_cast<const bf16x8*>(p);
}

__device__ inline bf16x8 cvt8(const float* src) {
    float v[8];
    *reinterpret_cast<float4*>(&v[0]) = *reinterpret_cast<const float4*>(src);
    *reinterpret_cast<float4*>(&v[4]) = *reinterpret_cast<const float4*>(src + 4);
    bf16x8 r;
    #pragma unroll
    for (int j = 0; j < 8; ++j) r[j] = (short)f2bf(v[j]);
    return r;
}

// ---- one-time prep: WcatT[n][k] = bf16( k<512 ? Wk[k][n] : Wr[k-512][n] ) ----
// 32x32 tile transpose. grid (48 k-tiles, 96 n-tiles), block (32, 8).
__global__ void wprep(const float* __restrict__ Wk, const float* __restrict__ Wr,
                      unsigned short* __restrict__ WcatT) {
    __shared__ unsigned short S[32][33];
    const int kb = blockIdx.x * 32;
    const int nb = blockIdx.y * 32;
    const int tx = threadIdx.x;   // 0..31
    const int ty = threadIdx.y;   // 0..7
    #pragma unroll
    for (int j = 0; j < 4; ++j) {
        const int r = ty + 8 * j;         // k-local
        const int k = kb + r;
        const int n = nb + tx;
        const float v = (k < D_) ? Wk[(size_t)k * N3U + n]
                                 : Wr[(size_t)(k - D_) * N3U + n];
        S[tx][r] = f2bf(v);               // transposed store: S[n-local][k-local]
    }
    __syncthreads();
    #pragma unroll
    for (int j = 0; j < 4; ++j) {
        const int r = ty + 8 * j;         // n-local
        WcatT[(size_t)(nb + r) * K_TOT + kb + tx] = S[r][tx];
    }
}

// ---- per-timestep GEMM + gates. No LDS, no barriers. ----
// grid (32 u-blocks, 2 b-blocks), block 512 = 8 waves (4 b-waves x 2 u-waves).
// Wave tile 16b x 16u, 3 gates fused (z, r, h with split x/recurrent accums).
__global__ __launch_bounds__(512) void tgru_step_mfma(
    const float* __restrict__ seq,         // [B,T,D] fp32
    const float* __restrict__ dts,         // [B,T]
    const unsigned short* __restrict__ WcatT, // [3072][1536] bf16
    const float* __restrict__ ib,          // [3U]
    const float* __restrict__ rb,          // [3U]
    const unsigned short* __restrict__ hdecb_prev, // [B,U] bf16  (h*dec for this t)
    const float* __restrict__ hdecf_prev,  // [B,U] fp32 (h*dec for this t)
    unsigned short* __restrict__ hdecb_next,
    float* __restrict__ hdecf_next,
    float* __restrict__ out,               // [B,U] final h (written iff is_last)
    int t, int is_last)
{
    const int tid  = threadIdx.x;
    const int lane = tid & 63;
    const int w    = tid >> 6;            // 0..7
    const int wr   = w >> 1;              // 0..3 (b)
    const int wu   = w & 1;               // 0..1 (u)
    const int b_base = blockIdx.y * 64 + wr * 16;
    const int u_base = blockIdx.x * 32 + wu * 16;
    const int l15 = lane & 15;
    const int lk  = lane >> 4;            // k-group 0..3

    f32x4 accz  = {0.f, 0.f, 0.f, 0.f};
    f32x4 accr  = {0.f, 0.f, 0.f, 0.f};
    f32x4 acchx = {0.f, 0.f, 0.f, 0.f};
    f32x4 acchr = {0.f, 0.f, 0.f, 0.f};

    const int u = u_base + l15;
    // B-fragment row pointers (k-contiguous rows of WcatT), one per gate
    const unsigned short* bpz = WcatT + (size_t)(u)           * K_TOT + 8 * lk;
    const unsigned short* bpr = WcatT + (size_t)(U_ + u)      * K_TOT + 8 * lk;
    const unsigned short* bph = WcatT + (size_t)(2 * U_ + u)  * K_TOT + 8 * lk;

    // ---- phase X: k in [0, 512), A = bf16(seq[b][t][k]) ----
    {
        const float* ap = seq + ((size_t)(b_base + l15) * T_ + t) * D_ + 8 * lk;
        #pragma unroll 4
        for (int ks = 0; ks < D_ / 32; ++ks) {
            const bf16x8 a  = cvt8(ap + 32 * ks);
            const bf16x8 bz = ldb16(bpz + 32 * ks);
            const bf16x8 br = ldb16(bpr + 32 * ks);
            const bf16x8 bh = ldb16(bph + 32 * ks);
            accz  = __builtin_amdgcn_mfma_f32_16x16x32_bf16(a, bz, accz,  0, 0, 0);
            accr  = __builtin_amdgcn_mfma_f32_16x16x32_bf16(a, br, accr,  0, 0, 0);
            acchx = __builtin_amdgcn_mfma_f32_16x16x32_bf16(a, bh, acchx, 0, 0, 0);
        }
    }
    // ---- phase H: k in [512, 1536), A = hdecb_prev (already bf16) ----
    {
        const unsigned short* ap = hdecb_prev + (size_t)(b_base + l15) * U_ + 8 * lk;
        #pragma unroll 4
        for (int ks = 0; ks < U_ / 32; ++ks) {
            const bf16x8 a  = ldb16(ap + 32 * ks);
            const bf16x8 bz = ldb16(bpz + D_ + 32 * ks);
            const bf16x8 br = ldb16(bpr + D_ + 32 * ks);
            const bf16x8 bh = ldb16(bph + D_ + 32 * ks);
            accz  = __builtin_amdgcn_mfma_f32_16x16x32_bf16(a, bz, accz,  0, 0, 0);
            accr  = __builtin_amdgcn_mfma_f32_16x16x32_bf16(a, br, accr,  0, 0, 0);
            acchr = __builtin_amdgcn_mfma_f32_16x16x32_bf16(a, bh, acchr, 0, 0, 0);
        }
    }

    // ---- epilogue: gates, blend, pre-decay for next step ----
    const float bz_s = ib[u]          + rb[u];
    const float br_s = ib[U_ + u]     + rb[U_ + u];
    const float ibh  = ib[2 * U_ + u];
    const float rbh  = rb[2 * U_ + u];

    #pragma unroll
    for (int q = 0; q < 4; ++q) {
        const int b = b_base + lk * 4 + q;
        const float z  = 1.0f / (1.0f + expf(-(accz[q]  + bz_s)));
        const float r  = 1.0f / (1.0f + expf(-(accr[q]  + br_s)));
        const float hh = tanhf(acchx[q] + ibh + r * (acchr[q] + rbh));
        const float hdp = hdecf_prev[(size_t)b * U_ + u];
        const float hn  = z * hdp + (1.0f - z) * hh;
        if (is_last) {
            out[(size_t)b * U_ + u] = hn;
        } else {
            const float dn = 1.0f / logf(E_CONST + dts[b * T_ + t + 1]);
            const float hd = hn * dn;
            hdecf_next[(size_t)b * U_ + u] = hd;
            hdecb_next[(size_t)b * U_ + u] = f2bf(hd);
        }
    }
}

extern "C" void kernel_launch(void* const* d_in, const int* in_sizes, int n_in,
                              void* d_out, int out_size, void* d_ws, size_t ws_size,
                              hipStream_t stream) {
    const float* seq = (const float*)d_in[0];  // sequences [B,T,D]
    const float* dts = (const float*)d_in[1];  // time_deltas [B,T]
    const float* Wk  = (const float*)d_in[2];  // kernel [D,3U]
    const float* Wr  = (const float*)d_in[3];  // recurrent_kernel [U,3U]
    const float* ib  = (const float*)d_in[4];  // input_bias [3U]
    const float* rb  = (const float*)d_in[5];  // recurrent_bias [3U]
    float* out = (float*)d_out;

    char* wsb = (char*)d_ws;
    // ws layout (bytes):
    //   [0, 9437184)            WcatT bf16 [3072][1536]
    //   [9437184, 9699328)      hdecb A  [128][1024] bf16
    //   [9699328, 9961472)      hdecb B
    //   [9961472, 10485760)     hdecf A  [128][1024] fp32
    //   [10485760, 11010048)    hdecf B
    unsigned short* wcat = (unsigned short*)(wsb);
    unsigned short* hb[2] = { (unsigned short*)(wsb + 9437184),
                              (unsigned short*)(wsb + 9699328) };
    float* hf[2] = { (float*)(wsb + 9961472), (float*)(wsb + 10485760) };

    // h0 = 0: zero the t=0 "prev" buffers (A side).
    hipMemsetAsync(hb[0], 0, 262144, stream);
    hipMemsetAsync(hf[0], 0, 524288, stream);

    wprep<<<dim3(K_TOT / 32, N3U / 32), dim3(32, 8), 0, stream>>>(Wk, Wr, wcat);

    for (int t = 0; t < T_; ++t) {
        const int p = t & 1;       // prev index
        const int n = p ^ 1;       // next index
        tgru_step_mfma<<<dim3(U_ / 32, B_ / 64), 512, 0, stream>>>(
            seq, dts, wcat, ib, rb,
            hb[p], hf[p], hb[n], hf[n],
            out, t, (t == T_ - 1) ? 1 : 0);
    }
}